// Round 5
// baseline (452.519 us; speedup 1.0000x reference)
//
#include <hip/hip_runtime.h>
#include <math.h>

#define DEV __device__ __forceinline__

typedef unsigned short u16;
typedef unsigned int   u32;
typedef __bf16 bf16x8 __attribute__((ext_vector_type(8)));
typedef float  f32x4  __attribute__((ext_vector_type(4)));
typedef u16    u16x8  __attribute__((ext_vector_type(8)));
typedef u16    u16x4  __attribute__((ext_vector_type(4)));

// ---------- helpers ----------
DEV u16 f2b(float f) {                 // f32 -> bf16 RNE
  u32 u = __builtin_bit_cast(u32, f);
  u = (u + 0x7FFFu + ((u >> 16) & 1u)) >> 16;
  return (u16)u;
}
DEV float b2f(u16 h) { u32 u = (u32)h << 16; return __builtin_bit_cast(float, u); }

DEV void gl_lds16(const u16* g, u16* l) {  // async global->LDS, 16B/lane (lds ptr wave-uniform)
  __builtin_amdgcn_global_load_lds((const __attribute__((address_space(1))) void*)g,
                                   (__attribute__((address_space(3))) void*)l, 16, 0, 0);
}

DEV float wred_max(float v) {
#pragma unroll
  for (int o = 32; o > 0; o >>= 1) v = fmaxf(v, __shfl_xor(v, o, 64));
  return v;
}
DEV float wred_sum(float v) {
#pragma unroll
  for (int o = 32; o > 0; o >>= 1) v += __shfl_xor(v, o, 64);
  return v;
}

// ---------- concat emb1|emb2 and convert to bf16 ----------
__global__ __launch_bounds__(256) void concat_convert(
    const float* __restrict__ e1, const float* __restrict__ e2, u16* __restrict__ xb) {
  const size_t idx = ((size_t)blockIdx.x * 256 + threadIdx.x) * 8;  // 8 elems/thread
  const int d = (int)(idx & 1023);
  const size_t row = idx >> 10;
  const float* s = (d < 512) ? (e1 + row * 512 + d) : (e2 + row * 512 + (d - 512));
  f32x4 a = *(const f32x4*)s;
  f32x4 b = *(const f32x4*)(s + 4);
  u16x8 o;
  o[0]=f2b(a[0]); o[1]=f2b(a[1]); o[2]=f2b(a[2]); o[3]=f2b(a[3]);
  o[4]=f2b(b[0]); o[5]=f2b(b[1]); o[6]=f2b(b[2]); o[7]=f2b(b[3]);
  *(u16x8*)(xb + idx) = o;
}

// ---------- transpose f32 [K][N] -> bf16 [N][K] (weights) ----------
__global__ __launch_bounds__(256) void transpose_w(
    const float* __restrict__ W, int ldi, u16* __restrict__ WT, int ldo) {
  __shared__ float tile[64][65];
  const int tx = threadIdx.x & 63, ty = threadIdx.x >> 6;
  const int r0 = blockIdx.y * 64, c0 = blockIdx.x * 64;
#pragma unroll
  for (int i = 0; i < 16; ++i)
    tile[ty + 4*i][tx] = W[(size_t)(r0 + ty + 4*i) * ldi + c0 + tx];
  __syncthreads();
#pragma unroll
  for (int i = 0; i < 16; ++i)
    WT[(size_t)(c0 + ty + 4*i) * ldo + r0 + tx] = f2b(tile[tx][ty + 4*i]);
}

// ---------- fused q|k bias (2048) ----------
__global__ void concat_bias(const float* __restrict__ bq, const float* __restrict__ bk,
                            float* __restrict__ o) {
  int i = blockIdx.x * 256 + threadIdx.x;  // 2048 total
  o[i] = (i < 1024) ? bq[i] : bk[i - 1024];
}

// ============================================================================
// 128x128 bf16 GEMM: C = act(scale * A[M,K] x B^T[N,K] + bias)
// 256 threads (4 waves 2x2, wave tile 64x64, 4x4 16x16x32 frags), BK=32.
// 3-buffer LDS ring (48 KB) -> 3 blocks/CU co-resident: cross-block desync
// overlaps one block's LDS-read drain with another's MFMA (m114/m97 mechanism),
// breaking the intra-block barrier lockstep that capped r2-r4 at ~31% MfmaUtil.
// Counted vmcnt(4) (never drain-0 mid-loop). Race ledger:
//  - stage(kt+2) -> ring[(kt+2)%3] == ring[(kt-1)%3]: tile kt-1's reads were all
//    lgkm-consumed inside body kt-1 (before its end barrier); stage issues in
//    body kt, strictly after that barrier -> no overwrite race.
//  - reads of tile kt: staged in body kt-2 (4 loads); only body kt-1's 4 stage
//    loads were issued after them, so end-of-body-(kt-1) vmcnt(4) proves tile
//    kt landed; barrier makes it collective across waves.
//  - tail: body KT-2 stages nothing -> vmcnt(0) drains tile KT-1.
// LDS XOR swizzle (granule ^= (row>>1)&3) on pre-swizzled global source +
// swizzled ds_read -> 0 bank conflicts (verified r2). XCD slab swizzle.
// ============================================================================
template<int F32OUT, int RELU, int RBIAS>
__global__ __launch_bounds__(256, 3) void gemm128(
    const u16* __restrict__ A, int lda, long long sA,
    const u16* __restrict__ B, int ldb, long long sB,
    void* __restrict__ C, int ldc, long long sC,
    const float* __restrict__ bias, float scale, int K) {
  __shared__ __align__(16) u16 sm[3 * 8192];   // ring of {A[128][32], B[128][32]}

  const int t  = threadIdx.x;
  const int ln = t & 63, wv = t >> 6;

  // --- 2D-chunked bijective XCD swizzle (all grids: nwg % 8 == 0, gy % 8 == 0) ---
  int bx, by, bz;
  {
    const int gx = gridDim.x, gy = gridDim.y, gz = gridDim.z;
    const int nwg = gx * gy * gz;
    const int F = (blockIdx.z * gy + blockIdx.y) * gx + blockIdx.x;
    const int q = nwg >> 3;
    const int L = (F & 7) * q + (F >> 3);        // XCD k executes L in [k*q,(k+1)*q)
    if (gz > 1) {
      const int pb = gx * gy;
      bz = L / pb; const int r = L - bz * pb;
      by = r / gx; bx = r - by * gx;             // batch-major: whole batches per XCD
    } else {
      bz = 0;
      const int sw = gx * 8;                     // slab = 8 by-rows x all bx
      const int sy = L / sw; const int r = L - sy * sw;
      bx = r >> 3; by = sy * 8 + (r & 7);        // A-slab L2-resident per XCD
    }
  }
  const int m0 = by * 128, n0 = bx * 128;
  A += (size_t)bz * (size_t)sA; B += (size_t)bz * (size_t)sB;

  // staging: thread t -> row (t>>2) [0..63, +64 for 2nd inst], granule t&3;
  // pre-swizzled source granule = (t&3) ^ ((t>>3)&3)
  const int srow = t >> 2;
  const int sgr  = (t & 3) ^ ((t >> 3) & 3);
  const u16* gA = A + (size_t)(m0 + srow) * lda + sgr * 8;
  const u16* gB = B + (size_t)(n0 + srow) * ldb + sgr * 8;
  const size_t a64 = (size_t)64 * lda, b64 = (size_t)64 * ldb;
  const int ldst = wv * 512;                     // wave-uniform elems within 2048-elem chunk

  const int l15 = ln & 15, lhi = ln >> 4;
  const int wm = (wv >> 1) * 64, wn = (wv & 1) * 64;

  // per-frag swizzled LDS offsets (elems): row r, granule lhi ^ ((r>>1)&3)
  int offA[4], offB[4];
#pragma unroll
  for (int i = 0; i < 4; ++i) {
    const int r = wm + i * 16 + l15;
    offA[i] = r * 32 + ((lhi ^ ((r >> 1) & 3)) << 3);
  }
#pragma unroll
  for (int j = 0; j < 4; ++j) {
    const int r = wn + j * 16 + l15;
    offB[j] = 4096 + r * 32 + ((lhi ^ ((r >> 1) & 3)) << 3);
  }

  f32x4 acc[4][4] = {};
  const int KT = K >> 5;

#define STAGE(tile)                                                       \
  {                                                                       \
    const int rb = (tile) % 3;                                            \
    const u16* _ga = gA + (size_t)(tile) * 32;                            \
    const u16* _gb = gB + (size_t)(tile) * 32;                            \
    u16* _la = &sm[rb * 8192 + ldst];                                     \
    u16* _lb = &sm[rb * 8192 + 4096 + ldst];                              \
    gl_lds16(_ga, _la); gl_lds16(_ga + a64, _la + 2048);                  \
    gl_lds16(_gb, _lb); gl_lds16(_gb + b64, _lb + 2048);                  \
  }

  // prologue: stage tiles 0,1 (8 per-wave loads); drain tile 0 (vmcnt(4))
  STAGE(0); STAGE(1);
  asm volatile("s_waitcnt vmcnt(4)" ::: "memory");
  __builtin_amdgcn_sched_barrier(0);
  __builtin_amdgcn_s_barrier();

  for (int kt = 0; kt < KT; ++kt) {
    const int rb = kt % 3;
    const u16* Ab = &sm[rb * 8192];

    if (kt + 2 < KT) STAGE(kt + 2);

    bf16x8 a0 = *(const bf16x8*)&Ab[offA[0]];
    bf16x8 a1 = *(const bf16x8*)&Ab[offA[1]];
    bf16x8 a2 = *(const bf16x8*)&Ab[offA[2]];
    bf16x8 a3 = *(const bf16x8*)&Ab[offA[3]];
    bf16x8 b0 = *(const bf16x8*)&Ab[offB[0]];
    bf16x8 b1 = *(const bf16x8*)&Ab[offB[1]];
    bf16x8 b2 = *(const bf16x8*)&Ab[offB[2]];
    bf16x8 b3 = *(const bf16x8*)&Ab[offB[3]];

    __builtin_amdgcn_s_setprio(1);
    acc[0][0] = __builtin_amdgcn_mfma_f32_16x16x32_bf16(a0, b0, acc[0][0], 0, 0, 0);
    acc[0][1] = __builtin_amdgcn_mfma_f32_16x16x32_bf16(a0, b1, acc[0][1], 0, 0, 0);
    acc[0][2] = __builtin_amdgcn_mfma_f32_16x16x32_bf16(a0, b2, acc[0][2], 0, 0, 0);
    acc[0][3] = __builtin_amdgcn_mfma_f32_16x16x32_bf16(a0, b3, acc[0][3], 0, 0, 0);
    acc[1][0] = __builtin_amdgcn_mfma_f32_16x16x32_bf16(a1, b0, acc[1][0], 0, 0, 0);
    acc[1][1] = __builtin_amdgcn_mfma_f32_16x16x32_bf16(a1, b1, acc[1][1], 0, 0, 0);
    acc[1][2] = __builtin_amdgcn_mfma_f32_16x16x32_bf16(a1, b2, acc[1][2], 0, 0, 0);
    acc[1][3] = __builtin_amdgcn_mfma_f32_16x16x32_bf16(a1, b3, acc[1][3], 0, 0, 0);
    acc[2][0] = __builtin_amdgcn_mfma_f32_16x16x32_bf16(a2, b0, acc[2][0], 0, 0, 0);
    acc[2][1] = __builtin_amdgcn_mfma_f32_16x16x32_bf16(a2, b1, acc[2][1], 0, 0, 0);
    acc[2][2] = __builtin_amdgcn_mfma_f32_16x16x32_bf16(a2, b2, acc[2][2], 0, 0, 0);
    acc[2][3] = __builtin_amdgcn_mfma_f32_16x16x32_bf16(a2, b3, acc[2][3], 0, 0, 0);
    acc[3][0] = __builtin_amdgcn_mfma_f32_16x16x32_bf16(a3, b0, acc[3][0], 0, 0, 0);
    acc[3][1] = __builtin_amdgcn_mfma_f32_16x16x32_bf16(a3, b1, acc[3][1], 0, 0, 0);
    acc[3][2] = __builtin_amdgcn_mfma_f32_16x16x32_bf16(a3, b2, acc[3][2], 0, 0, 0);
    acc[3][3] = __builtin_amdgcn_mfma_f32_16x16x32_bf16(a3, b3, acc[3][3], 0, 0, 0);
    __builtin_amdgcn_s_setprio(0);

    // counted wait: tile kt+1 landed (only body-kt's 4 stage loads remain)
    if (kt < KT - 2)       { asm volatile("s_waitcnt vmcnt(4)" ::: "memory"); }
    else if (kt == KT - 2) { asm volatile("s_waitcnt vmcnt(0)" ::: "memory"); }
    if (kt < KT - 1) {
      __builtin_amdgcn_sched_barrier(0);
      __builtin_amdgcn_s_barrier();
    }
  }
#undef STAGE

  // epilogue: frag D row=(lhi*4+r), col=l15 (m89-verified layout)
  const size_t cb = (size_t)bz * (size_t)sC;
#pragma unroll
  for (int i = 0; i < 4; ++i) {
    const int rg = m0 + wm + i * 16 + lhi * 4;
#pragma unroll
    for (int j = 0; j < 4; ++j) {
      const int cg = n0 + wn + j * 16 + l15;
      const float cbv = (!RBIAS && bias) ? bias[cg] : 0.f;
#pragma unroll
      for (int r = 0; r < 4; ++r) {
        float v = acc[i][j][r] * scale + (RBIAS ? bias[rg + r] : cbv);
        if (RELU) v = fmaxf(v, 0.f);
        if (F32OUT) ((float*)C)[cb + (size_t)(rg + r) * ldc + cg] = v;
        else        ((u16*)C)[cb + (size_t)(rg + r) * ldc + cg] = f2b(v);
      }
    }
  }
}

// ---------- row softmax with query-row mask, f32 scores -> bf16 attn ----------
__global__ __launch_bounds__(256) void softmax_mask(
    const float* __restrict__ sc, const int* __restrict__ m1,
    const int* __restrict__ m2, u16* __restrict__ attn) {
  __shared__ float red[8];
  const int row = blockIdx.x;            // b*1024 + q
  const int b = row >> 10, q = row & 1023;
  const int mk = (q < 512) ? m1[b * 512 + q] : m2[b * 512 + q - 512];
  f32x4 v = ((const f32x4*)(sc + (size_t)row * 1024))[threadIdx.x];
  if (mk == 0) { v[0] = v[1] = v[2] = v[3] = -INFINITY; }
  float mx = fmaxf(fmaxf(v[0], v[1]), fmaxf(v[2], v[3]));
  mx = wred_max(mx);
  const int ln = threadIdx.x & 63, wv = threadIdx.x >> 6;
  if (ln == 0) red[wv] = mx;
  __syncthreads();
  mx = fmaxf(fmaxf(red[0], red[1]), fmaxf(red[2], red[3]));
  float e0 = __expf(v[0] - mx), e1 = __expf(v[1] - mx);
  float e2 = __expf(v[2] - mx), e3 = __expf(v[3] - mx);
  float s = wred_sum(e0 + e1 + e2 + e3);
  if (ln == 0) red[4 + wv] = s;
  __syncthreads();
  const float inv = 1.f / (red[4] + red[5] + red[6] + red[7]);
  u16x4 o; o[0] = f2b(e0 * inv); o[1] = f2b(e1 * inv); o[2] = f2b(e2 * inv); o[3] = f2b(e3 * inv);
  *(u16x4*)(attn + (size_t)row * 1024 + threadIdx.x * 4) = o;
}

// ---------- final: sigmoid(h2 . W3 + b3), one wave per row ----------
__global__ __launch_bounds__(256) void logits_sigmoid(
    const u16* __restrict__ h2, const float* __restrict__ W3,
    const float* __restrict__ b3, float* __restrict__ out) {
  const int wid = (blockIdx.x * 256 + threadIdx.x) >> 6;  // row
  const int ln = threadIdx.x & 63;
  const u16* r = h2 + (size_t)wid * 1024 + ln * 16;
  u16x8 v0 = *(const u16x8*)r;
  u16x8 v1 = *(const u16x8*)(r + 8);
  const float* w = W3 + ln * 16;
  float s = 0.f;
#pragma unroll
  for (int i = 0; i < 8; ++i) s += b2f(v0[i]) * w[i];
#pragma unroll
  for (int i = 0; i < 8; ++i) s += b2f(v1[i]) * w[8 + i];
#pragma unroll
  for (int o = 32; o > 0; o >>= 1) s += __shfl_down(s, o, 64);
  if (ln == 0) out[wid] = 1.f / (1.f + __expf(-(s + b3[0])));
}

// ---------- launcher ----------
extern "C" void kernel_launch(void* const* d_in, const int* in_sizes, int n_in,
                              void* d_out, int out_size, void* d_ws, size_t ws_size,
                              hipStream_t stream) {
  (void)in_sizes; (void)n_in; (void)out_size; (void)ws_size;
  const float* emb1 = (const float*)d_in[0];
  const float* emb2 = (const float*)d_in[1];
  const int*   mask1 = (const int*)d_in[2];
  const int*   mask2 = (const int*)d_in[3];
  const float* Wq = (const float*)d_in[4];  const float* bq = (const float*)d_in[5];
  const float* Wk = (const float*)d_in[6];  const float* bk = (const float*)d_in[7];
  const float* Wv = (const float*)d_in[8];  const float* bv = (const float*)d_in[9];
  const float* W1 = (const float*)d_in[10]; const float* b1 = (const float*)d_in[11];
  const float* W2 = (const float*)d_in[12]; const float* b2 = (const float*)d_in[13];
  const float* W3 = (const float*)d_in[14]; const float* b3 = (const float*)d_in[15];

  // ws layout (bytes), hand-aliased; peak ~216 MiB
  char* ws = (char*)d_ws;
  u16*  XB    = (u16*)(ws + 0);            // [16384][1024] bf16; later ATTN
  u16*  QK    = (u16*)(ws + 33554432);     // [16384][2048] bf16 (Q|K); later H1
  u16*  VT    = (u16*)(ws + 100663296);    // [1024][16384] bf16 (V^T); later H2
  float* SC   = (float*)(ws + 134217728);  // [16][1024][1024] f32; later ATT
  u16*  WTQKV = (u16*)(ws + 201326592);    // [3072][1024] bf16 (WqT|WkT|WvT)
  u16*  W1T   = (u16*)(ws + 207618048);    // [2048][1024] bf16
  u16*  W2T   = (u16*)(ws + 211812352);    // [1024][2048] bf16
  float* BF_  = (float*)(ws + 216006656);  // [2048] f32 (bq|bk)
  u16*  ATTN  = XB;                        // XB dead after V-GEMM
  u16*  ATT   = (u16*)(ws + 134217728);    // SC dead after softmax
  u16*  H1    = QK;                        // QK dead after scores GEMM
  u16*  H2    = VT;                        // VT dead after PV GEMM
  float* out  = (float*)d_out;

  const float SCALE = 0.04419417382415922f;  // 1/sqrt(512)

  concat_convert<<<8192, 256, 0, stream>>>(emb1, emb2, XB);
  transpose_w<<<dim3(16, 16), 256, 0, stream>>>(Wq, 1024, WTQKV, 1024);
  transpose_w<<<dim3(16, 16), 256, 0, stream>>>(Wk, 1024, WTQKV + 1024 * 1024, 1024);
  transpose_w<<<dim3(16, 16), 256, 0, stream>>>(Wv, 1024, WTQKV + 2048 * 1024, 1024);
  transpose_w<<<dim3(32, 16), 256, 0, stream>>>(W1, 2048, W1T, 1024);
  transpose_w<<<dim3(16, 32), 256, 0, stream>>>(W2, 1024, W2T, 2048);
  concat_bias<<<8, 256, 0, stream>>>(bq, bk, BF_);

  // Q|K: [16384,1024] x [1024,2048]^T-layout -> bf16 [16384,2048]
  gemm128<0, 0, 0><<<dim3(16, 128, 1), 256, 0, stream>>>(
      XB, 1024, 0, WTQKV, 1024, 0, QK, 2048, 0, BF_, 1.f, 1024);
  // V^T directly: VT[d, b*S+s] = sum_k WvT[d,k] * XB[b*S+s,k] + bv[d] (row bias)
  gemm128<0, 0, 1><<<dim3(128, 8, 1), 256, 0, stream>>>(
      WTQKV + 2048 * 1024, 1024, 0, XB, 1024, 0, VT, 16384, 0, bv, 1.f, 1024);
  // scores = scale * Q K^T : batched, f32 out
  gemm128<1, 0, 0><<<dim3(8, 8, 16), 256, 0, stream>>>(
      QK, 2048, 2097152LL, QK + 1024, 2048, 2097152LL,
      SC, 1024, 1048576LL, nullptr, SCALE, 1024);
  softmax_mask<<<16384, 256, 0, stream>>>(SC, mask1, mask2, ATTN);
  // attended = attn @ V : batched; B-operand = VT rows (batch offset = bz*1024 elems)
  gemm128<0, 0, 0><<<dim3(8, 8, 16), 256, 0, stream>>>(
      ATTN, 1024, 1048576LL, VT, 16384, 1024LL,
      ATT, 1024, 1048576LL, nullptr, 1.f, 1024);
  // MLP
  gemm128<0, 1, 0><<<dim3(16, 128, 1), 256, 0, stream>>>(
      ATT, 1024, 0, W1T, 1024, 0, H1, 2048, 0, b1, 1.f, 1024);
  gemm128<0, 1, 0><<<dim3(8, 128, 1), 256, 0, stream>>>(
      H1, 2048, 0, W2T, 2048, 0, H2, 1024, 0, b2, 1.f, 2048);
  logits_sigmoid<<<4096, 256, 0, stream>>>(H2, W3, b3, out);
}